// Round 2
// baseline (177.944 us; speedup 1.0000x reference)
//
#include <hip/hip_runtime.h>
#include <hip/hip_fp16.h>
#include <stdint.h>

#define DIM 256
#define KE  768

typedef _Float16 half8 __attribute__((ext_vector_type(8)));
typedef float floatx4 __attribute__((ext_vector_type(4)));

// Workspace layout (bytes):
//   Xe    : 8192*768 ushort @ 0          (12,582,912)  [xh*64 | xh | xl*2^11]
//   We    : 5376*768 ushort @ 12582912   ( 8,257,536)  [wh*32 | wl*2^11 | wh]
//   wnorm : 5376 float      @ 20840448
//   xnorm : 8192 float      @ 20861952
//   best  : 24576 u64       @ 20894720   (level*8192+row) packed (d2<<32)|idx
#define WS_WE_OFF    12582912
#define WS_WNORM_OFF 20840448
#define WS_XNORM_OFF 20861952
#define WS_BEST_OFF  20894720

// One wave per row: fp32 norm + fp16 hi/lo split into the expanded layouts.
// Segment pairing in the GEMM: (xh*64)*(wh*32) = 2^11*xh*wh ; xh*(wl*2^11) ;
// (xl*2^11)*wh  => acc = 2^11 * (xh*wh + xh*wl + xl*wh), no mid-loop rescale.
__global__ __launch_bounds__(256) void conv_kernel(
    const float* __restrict__ x, const float* __restrict__ w1,
    const float* __restrict__ w2, const float* __restrict__ w3,
    ushort* __restrict__ Xe, ushort* __restrict__ We,
    float* __restrict__ wnorm, float* __restrict__ xnorm) {
  int task = blockIdx.x * 4 + (threadIdx.x >> 6);
  int lane = threadIdx.x & 63;
  const float* src; ushort* dst; float* ndst; int isx;
  if (task < 8192) {
    src = x + (size_t)task * DIM; dst = Xe + (size_t)task * KE;
    ndst = xnorm + task; isx = 1;
  } else {
    int wi = task - 8192;
    if (wi < 256)       src = w1 + (size_t)wi * DIM;
    else if (wi < 1280) src = w2 + (size_t)(wi - 256) * DIM;
    else                src = w3 + (size_t)(wi - 1280) * DIM;
    dst = We + (size_t)wi * KE; ndst = wnorm + wi; isx = 0;
  }
  float4 v = *(const float4*)(src + lane * 4);
  float fv[4] = {v.x, v.y, v.z, v.w};
  float s = fv[0]*fv[0] + fv[1]*fv[1] + fv[2]*fv[2] + fv[3]*fv[3];
  #pragma unroll
  for (int o = 32; o > 0; o >>= 1) s += __shfl_xor(s, o);
  if (lane == 0) *ndst = s;

  float scale = isx ? 64.0f : 32.0f;
  ushort h[4], hs[4], l[4];
  #pragma unroll
  for (int e = 0; e < 4; ++e) {
    __half hh = __float2half(fv[e]);
    float hf = __half2float(hh);
    h[e]  = __half_as_ushort(hh);
    hs[e] = __half_as_ushort(__float2half(hf * scale));       // exact (pow2)
    l[e]  = __half_as_ushort(__float2half((fv[e] - hf) * 2048.0f));
  }
  ushort4 h4 = make_ushort4(h[0], h[1], h[2], h[3]);
  ushort4 s4 = make_ushort4(hs[0], hs[1], hs[2], hs[3]);
  ushort4 l4 = make_ushort4(l[0], l[1], l[2], l[3]);
  if (isx) {  // [xh*64 | xh | xl2]
    *(ushort4*)(dst + lane * 4)        = s4;
    *(ushort4*)(dst + 256 + lane * 4)  = h4;
    *(ushort4*)(dst + 512 + lane * 4)  = l4;
  } else {    // [wh*32 | wl2 | wh]
    *(ushort4*)(dst + lane * 4)        = s4;
    *(ushort4*)(dst + 256 + lane * 4)  = l4;
    *(ushort4*)(dst + 512 + lane * 4)  = h4;
  }
}

// 256x256-tile, 8-wave (2Mx4N), pipelined MFMA GEMM over K=768 with fused
// per-row argmin. m201-aligned schedule: raw s_barrier + counted vmcnt,
// NO sched_barrier pins (m141 trap), split fragment regs (av0/av1, bv
// read once per pair) so LDS-read latency can overlap MFMA.
// Ring: 4 slots per operand of K-half (32-elem) slabs; steady-state
// vmcnt(4) once per pair, vmcnt(0) only at drain.
// grid.x = 32 row-blocks, grid.y = 21 col-blocks (1 | 4 | 16 per level).
__global__ __launch_bounds__(512, 2) void gemm_kernel(
    const ushort* __restrict__ Xe, const ushort* __restrict__ We,
    const float* __restrict__ xnorm, const float* __restrict__ wnorm,
    unsigned long long* __restrict__ best) {
  // A ring: ushorts [0, 32768)  = 4 slots x 8192 ushorts (256 rows x 32)
  // B ring: ushorts [32768, 65536)
  __shared__ __align__(16) ushort AB[65536];
  __shared__ unsigned long long red[4][256];

  const int t = threadIdx.x;
  const int w = t >> 6;
  const int lane = t & 63;
  const int ln = lane & 15, q = lane >> 4;
  const int wr = w >> 2, wc = w & 3;          // 2 x 4 wave grid
  const int r0 = blockIdx.x * 256;
  const int cb = blockIdx.y;
  const int n0 = cb << 8;
  int level, lbase;
  if (cb < 1)      { level = 0; lbase = 0; }
  else if (cb < 5) { level = 1; lbase = 256; }
  else             { level = 2; lbase = 1280; }

  // Fragment LDS byte offsets. Row r, K-quarter q -> chunk (q ^ ((r>>1)&3)):
  // conflict-free ds_read_b128 (row-pairs share a chunk = free 2-way).
  int aoff[2][4], boff[4];
  #pragma unroll
  for (int mh = 0; mh < 2; ++mh)
    #pragma unroll
    for (int mt = 0; mt < 4; ++mt) {
      int ra = wr * 128 + mh * 64 + mt * 16 + ln;
      aoff[mh][mt] = ra * 64 + ((q ^ ((ra >> 1) & 3)) << 4);
    }
  #pragma unroll
  for (int nt = 0; nt < 4; ++nt) {
    int rb = wc * 64 + nt * 16 + ln;
    boff[nt] = 65536 + rb * 64 + ((q ^ ((rb >> 1) & 3)) << 4);
  }
  const char* ABb = (const char*)AB;

  // Staging: one slab = 256 rows x 4 chunks; wave w covers rows w*16..+16
  // (round 0) and +128 (round 1). LDS dest linear (wave-uniform base +
  // lane*16); global source pre-swizzled with the same XOR -> involution.
  const int sr = (w << 4) + (lane >> 2);
  const int sc = lane & 3;
  const int sg = sc ^ ((sr >> 1) & 3);        // same for sr and sr+128
  const ushort* srcA0 = Xe + (size_t)(r0 + sr) * KE + sg * 8;
  const ushort* srcB0 = We + (size_t)(n0 + sr) * KE + sg * 8;
  const int ldsO0 = w << 9;                   // ushorts
  const int ldsO1 = 4096 + (w << 9);          // rows +128

#define GLD(src_, dstoff_) __builtin_amdgcn_global_load_lds( \
    (const __attribute__((address_space(1))) void*)(src_), \
    (__attribute__((address_space(3))) void*)(AB + (dstoff_)), 16, 0, 0)
#define STAGE_A(pA_, slot_, koff_) do { \
    GLD((pA_) + (koff_) * 32,            ((slot_) << 13) + ldsO0); \
    GLD((pA_) + 128 * KE + (koff_) * 32, ((slot_) << 13) + ldsO1); } while (0)
#define STAGE_B(pB_, slot_, koff_) do { \
    GLD((pB_) + (koff_) * 32,            32768 + ((slot_) << 13) + ldsO0); \
    GLD((pB_) + 128 * KE + (koff_) * 32, 32768 + ((slot_) << 13) + ldsO1); } while (0)

  floatx4 acc[8][4];
  #pragma unroll
  for (int i = 0; i < 8; ++i)
    #pragma unroll
    for (int j = 0; j < 4; ++j) acc[i][j] = (floatx4)0.0f;

#define MFMA16(base_, av_) \
    _Pragma("unroll") for (int mt = 0; mt < 4; ++mt) \
      _Pragma("unroll") for (int nt = 0; nt < 4; ++nt) \
        acc[(base_) + mt][nt] = __builtin_amdgcn_mfma_f32_16x16x32_f16( \
            av_[mt], bv[nt], acc[(base_) + mt][nt], 0, 0, 0);

// One pair = K-half S_ (slot literal). PH0: m-tiles 0..3, PH1: 4..7.
// Stage slot S_+2 (A in PH0, B in PH1). VMW_ once per pair (end), counted.
#define PAIR(S_, pA_, pB_, K_, STG_, VMW_) do { \
    const int sb_ = (S_) << 14; \
    half8 av0[4], av1[4], bv[4]; \
    _Pragma("unroll") for (int mt = 0; mt < 4; ++mt) \
      av0[mt] = *(const half8*)(ABb + sb_ + aoff[0][mt]); \
    _Pragma("unroll") for (int nt = 0; nt < 4; ++nt) \
      bv[nt] = *(const half8*)(ABb + sb_ + boff[nt]); \
    if (STG_) STAGE_A(pA_, ((S_) + 2) & 3, (K_) + 2); \
    __builtin_amdgcn_s_barrier(); \
    __builtin_amdgcn_s_setprio(1); \
    MFMA16(0, av0) \
    __builtin_amdgcn_s_setprio(0); \
    __builtin_amdgcn_s_barrier(); \
    _Pragma("unroll") for (int mt = 0; mt < 4; ++mt) \
      av1[mt] = *(const half8*)(ABb + sb_ + aoff[1][mt]); \
    if (STG_) STAGE_B(pB_, ((S_) + 2) & 3, (K_) + 2); \
    __builtin_amdgcn_s_barrier(); \
    __builtin_amdgcn_s_setprio(1); \
    MFMA16(4, av1) \
    __builtin_amdgcn_s_setprio(0); \
    VMW_; \
    __builtin_amdgcn_s_barrier(); \
  } while (0)

#define VM4 asm volatile("s_waitcnt vmcnt(4)" ::: "memory")
#define VM0 asm volatile("s_waitcnt vmcnt(0)" ::: "memory")

  // Prologue: stage slots 0,1; newest 4 (slot 1) may stay outstanding.
  STAGE_A(srcA0, 0, 0); STAGE_B(srcB0, 0, 0);
  STAGE_A(srcA0, 1, 1); STAGE_B(srcB0, 1, 1);
  VM4;
  __builtin_amdgcn_s_barrier();

  const ushort* pA = srcA0;
  const ushort* pB = srcB0;
  #pragma unroll 1
  for (int hb = 0; hb < 20; hb += 4) {
    PAIR(0, pA, pB, 0, 1, VM4);
    PAIR(1, pA, pB, 1, 1, VM4);
    PAIR(2, pA, pB, 2, 1, VM4);
    PAIR(3, pA, pB, 3, 1, VM4);
    pA += 128; pB += 128;                     // 4 K-halves
  }
  // Tail: h=20..23 (pA at K-half 20). 20,21 still stage (K 22,23).
  PAIR(0, pA, pB, 0, 1, VM4);
  PAIR(1, pA, pB, 1, 1, VM4);
  PAIR(2, pA, pB, 2, 0, VM0);                 // drain: slot 3 fully landed
  PAIR(3, pA, pB, 3, 0, );

  // acc = 2^11 * dot. d2 = xn + wn - 2*dot = xn + wn - acc * 2^-10.
  float wnv[4];
  #pragma unroll
  for (int nt = 0; nt < 4; ++nt) wnv[nt] = wnorm[n0 + wc * 64 + nt * 16 + ln];

  #pragma unroll
  for (int mtg = 0; mtg < 8; ++mtg) {
    #pragma unroll
    for (int r = 0; r < 4; ++r) {
      int rowl = wr * 128 + mtg * 16 + q * 4 + r;
      float xnv = xnorm[r0 + rowl];
      unsigned long long bp = ~0ull;
      #pragma unroll
      for (int nt = 0; nt < 4; ++nt) {
        float d2 = fmaxf(xnv + wnv[nt] - acc[mtg][nt][r] * 0.0009765625f, 0.0f);
        unsigned col = (unsigned)(n0 + wc * 64 + nt * 16 + ln - lbase);
        unsigned long long p =
            ((unsigned long long)__float_as_uint(d2) << 32) | col;
        bp = (p < bp) ? p : bp;
      }
      #pragma unroll
      for (int off = 1; off < 16; off <<= 1) {
        unsigned long long o = __shfl_xor(bp, off);
        bp = (o < bp) ? o : bp;
      }
      if (ln == 0) red[wc][rowl] = bp;
    }
  }
  __syncthreads();
  if (t < 256) {
    unsigned long long m0 = red[0][t], m1 = red[1][t];
    unsigned long long m2 = red[2][t], m3 = red[3][t];
    unsigned long long m = m0 < m1 ? m0 : m1;
    if (m2 < m) m = m2;
    if (m3 < m) m = m3;
    atomicMin(&best[level * 8192 + r0 + t], m);
  }
}

// One wave per (level,row): coords + exact fp32 quantization error.
__global__ __launch_bounds__(256) void finalize_kernel(
    const float* __restrict__ x, const float* __restrict__ w1,
    const float* __restrict__ w2, const float* __restrict__ w3,
    const unsigned long long* __restrict__ best, float* __restrict__ out) {
  int task = blockIdx.x * 4 + (threadIdx.x >> 6);
  int lane = threadIdx.x & 63;
  int level = task >> 13;
  int row = task & 8191;
  const float* w; unsigned side;
  if (level == 0)      { w = w1; side = 16; }
  else if (level == 1) { w = w2; side = 32; }
  else                 { w = w3; side = 64; }
  unsigned idx = (unsigned)(best[level * 8192 + row] & 0xFFFFFFFFull);
  float4 xv = *(const float4*)(x + (size_t)row * DIM + lane * 4);
  float4 wv = *(const float4*)(w + (size_t)idx * DIM + lane * 4);
  float dx = xv.x - wv.x, dy = xv.y - wv.y, dz = xv.z - wv.z, dw = xv.w - wv.w;
  float s = dx * dx + dy * dy + dz * dz + dw * dw;
  #pragma unroll
  for (int o = 32; o > 0; o >>= 1) s += __shfl_xor(s, o);
  if (lane == 0) {
    out[level * 16384 + row * 2 + 0] = (float)(idx / side);
    out[level * 16384 + row * 2 + 1] = (float)(idx % side);
    out[49152 + level * 8192 + row] = sqrtf(s);
  }
}

extern "C" void kernel_launch(void* const* d_in, const int* in_sizes, int n_in,
                              void* d_out, int out_size, void* d_ws, size_t ws_size,
                              hipStream_t stream) {
  const float* x  = (const float*)d_in[0];
  const float* w1 = (const float*)d_in[1];
  const float* w2 = (const float*)d_in[2];
  const float* w3 = (const float*)d_in[3];
  ushort* Xe = (ushort*)d_ws;
  ushort* We = (ushort*)((char*)d_ws + WS_WE_OFF);
  float* wnorm = (float*)((char*)d_ws + WS_WNORM_OFF);
  float* xnorm = (float*)((char*)d_ws + WS_XNORM_OFF);
  unsigned long long* best = (unsigned long long*)((char*)d_ws + WS_BEST_OFF);

  hipMemsetAsync(best, 0xFF, 24576 * sizeof(unsigned long long), stream);
  conv_kernel<<<3392, 256, 0, stream>>>(x, w1, w2, w3, Xe, We, wnorm, xnorm);
  gemm_kernel<<<dim3(32, 21), 512, 0, stream>>>(Xe, We, xnorm, wnorm, best);
  finalize_kernel<<<6144, 256, 0, stream>>>(x, w1, w2, w3, best, (float*)d_out);
}